// Round 12
// baseline (233.629 us; speedup 1.0000x reference)
//
#include <hip/hip_runtime.h>

#define BS 64
#define TT 2048
#define NJ 24
#define ROWF 99            // 24*4 quats + 3 pos
#define BLOCK 128          // 2 waves over the SAME 64 rows: wave0 = X chain, wave1 = Y chain
#define RPB 64             // rows per block
#define NROWS (BS * TT)    // 131072 rows -> 2048 blocks -> 4096 waves (16/CU)

// 16B load at 4B alignment (rows are 396B-strided): gfx950 handles dword-aligned
// dwordx4 in HW.
__device__ __forceinline__ float4 ld4u(const float* __restrict__ p) {
  return *reinterpret_cast<const float4*>(p);
}

__device__ __forceinline__ void quat2mat_s(float w, float x, float y, float z,
                                           float s, float* R) {
  const float xx = s*x*x, yy = s*y*y, zz = s*z*z;
  const float xy = s*x*y, xz = s*x*z, yz = s*y*z;
  const float xw = s*x*w, yw = s*y*w, zw = s*z*w;
  R[0] = 1.0f - (yy+zz); R[1] = xy - zw;        R[2] = xz + yw;
  R[3] = xy + zw;        R[4] = 1.0f - (xx+zz); R[5] = yz - xw;
  R[6] = xz - yw;        R[7] = yz + xw;        R[8] = 1.0f - (xx+yy);
}

__device__ __forceinline__ void mm3(const float* A, const float* B, float* C) {
#pragma unroll
  for (int r = 0; r < 3; ++r) {
#pragma unroll
    for (int c = 0; c < 3; ++c) {
      C[3*r+c] = fmaf(A[3*r], B[c], fmaf(A[3*r+1], B[3+c], A[3*r+2]*B[6+c]));
    }
  }
}

// ROUND-12: X/Y WAVE-SPLIT. Evidence (rounds 1..11): achieved HBM BW scales with
// wave count (round 4: 3.35 TB/s @4096 waves), not per-wave schedule (all
// 8-wave/CU variants ~2 TB/s). This decomposition doubles waves with each
// thread carrying ONE chain (~90 live regs, no spill) and ONE array's loads.
// Coupling (rot/gtr diffs) is pipelined via LDS: X-wave writes window w's
// normalized quats + gtr; Y-wave runs one window behind, diffing against its
// own values. Double-buffered by window parity; 6 barriers; Y owns all
// accumulation. FK core unchanged: index-order walk, 3-slot liveness, rsqrt.
__global__ __launch_bounds__(BLOCK, 4) void motion_loss_kernel(
    const float* __restrict__ Ym, const float* __restrict__ Xm,
    const float* __restrict__ Yt, const float* __restrict__ Xt,
    float* __restrict__ out) {
  // X->Y handoff, [window parity][joint-in-window][row]; float4 -> 16B lane
  // stride -> conflict-free ds_read/write_b128. 16 KB total -> 8 blocks/CU.
  __shared__ float4 hq[2][4][RPB];   // X normalized quats (8 KB)
  __shared__ float4 hg[2][4][RPB];   // X global translations (8 KB)

  const int tid = threadIdx.x;
  const int t = tid & 63;                      // row within block
  const int side = tid >> 6;                   // 0 = X wave, 1 = Y wave
  const size_t row = (size_t)blockIdx.x * RPB + t;
  const int b = blockIdx.x >> 5;               // 32 blocks per batch (2048/64)
  const float* __restrict__ mr = (side ? Ym : Xm) + row * ROWF;
  const float* __restrict__ tv = (side ? Yt : Xt) + (size_t)b * NJ * 3;

  // own-array prefetch ring (round-7 pattern, halved: one array per wave)
  float4 ring[8];
#pragma unroll
  for (int k = 0; k < 8; ++k) ring[k] = ld4u(mr + 4 * k);
  const float4 pos = ld4u(mr + 95);   // floats [95..98]; pos = [96..98]

  float G[3][9], T[3][3];
  float rot_acc = 0.0f, gtr_acc = 0.0f, pos_acc = 0.0f;   // Y-wave only

#define ROOTSTEP do {                                                          \
    const float4 q = ring[0]; ring[0] = ld4u(mr + 32);                         \
    const float qq = q.x*q.x + q.y*q.y + q.z*q.z + q.w*q.w;                    \
    const float inv = rsqrtf(fmaxf(qq, 1e-24f));                               \
    const float4 nq = make_float4(q.x*inv, q.y*inv, q.z*inv, q.w*inv);         \
    quat2mat_s(q.x, q.y, q.z, q.w, 2.0f*inv*inv, G[0]);                        \
    T[0][0] = pos.y; T[0][1] = pos.z; T[0][2] = pos.w;                         \
    if (side == 0) {                                                           \
      hq[0][0][t] = nq;                                                        \
      hg[0][0][t] = make_float4(pos.y, pos.z, pos.w, 0.0f);                    \
    } else {                                                                   \
      const float4 nx = hq[0][0][t];                                           \
      const float r0 = nq.x-nx.x, r1 = nq.y-nx.y, r2 = nq.z-nx.z, r3 = nq.w-nx.w; \
      rot_acc += r0*r0 + r1*r1 + r2*r2 + r3*r3;                                \
      const float4 gx = hg[0][0][t];                                           \
      const float d0 = pos.y-gx.x, d1 = pos.z-gx.y, d2 = pos.w-gx.z;           \
      const float dd = d0*d0 + d1*d1 + d2*d2;                                  \
      gtr_acc += dd; pos_acc = dd;                                             \
    }                                                                          \
  } while (0)

#define JSTEP(j, PS, NS, WPAR) do {                                            \
    const float4 q = ring[(j) & 7];                                            \
    if ((j) + 8 < NJ) ring[(j) & 7] = ld4u(mr + 4*((j) + 8));                  \
    const float qq = q.x*q.x + q.y*q.y + q.z*q.z + q.w*q.w;                    \
    const float inv = rsqrtf(fmaxf(qq, 1e-24f));                               \
    const float4 nq = make_float4(q.x*inv, q.y*inv, q.z*inv, q.w*inv);         \
    const float t0 = tv[3*(j)], t1 = tv[3*(j)+1], t2 = tv[3*(j)+2];            \
    const float v0 = fmaf(G[PS][0],t0, fmaf(G[PS][1],t1, fmaf(G[PS][2],t2, T[PS][0]))); \
    const float v1 = fmaf(G[PS][3],t0, fmaf(G[PS][4],t1, fmaf(G[PS][5],t2, T[PS][1]))); \
    const float v2 = fmaf(G[PS][6],t0, fmaf(G[PS][7],t1, fmaf(G[PS][8],t2, T[PS][2]))); \
    float R[9], Gn[9];                                                         \
    quat2mat_s(q.x, q.y, q.z, q.w, 2.0f*inv*inv, R);                           \
    mm3(G[PS], R, Gn);                                                         \
    _Pragma("unroll")                                                          \
    for (int k = 0; k < 9; ++k) G[NS][k] = Gn[k];                              \
    T[NS][0] = v0; T[NS][1] = v1; T[NS][2] = v2;                               \
    if (side == 0) {                                                           \
      hq[WPAR][(j) & 3][t] = nq;                                               \
      hg[WPAR][(j) & 3][t] = make_float4(v0, v1, v2, 0.0f);                    \
    } else {                                                                   \
      const float4 nx = hq[WPAR][(j) & 3][t];                                  \
      const float r0 = nq.x-nx.x, r1 = nq.y-nx.y, r2 = nq.z-nx.z, r3 = nq.w-nx.w; \
      rot_acc += r0*r0 + r1*r1 + r2*r2 + r3*r3;                                \
      const float4 gx = hg[WPAR][(j) & 3][t];                                  \
      const float d0 = v0-gx.x, d1 = v1-gx.y, d2 = v2-gx.z;                    \
      gtr_acc += d0*d0 + d1*d1 + d2*d2;                                        \
    }                                                                          \
  } while (0)

  // windows over the index-order walk (slot schedule verified in round 7);
  // window w uses handoff parity w&1
#define WIN0 do { ROOTSTEP; JSTEP( 1,0,1,0); JSTEP( 2,0,2,0); JSTEP( 3,0,0,0); } while (0)
#define WIN1 do { JSTEP( 4,1,1,1); JSTEP( 5,2,2,1); JSTEP( 6,0,0,1); JSTEP( 7,1,1,1); } while (0)
#define WIN2 do { JSTEP( 8,2,2,0); JSTEP( 9,0,0,0); JSTEP(10,1,1,0); JSTEP(11,2,2,0); } while (0)
#define WIN3 do { JSTEP(12,0,1,1); JSTEP(13,0,2,1); JSTEP(14,0,0,1); JSTEP(15,1,1,1); } while (0)
#define WIN4 do { JSTEP(16,2,2,0); JSTEP(17,0,0,0); JSTEP(18,2,2,0); JSTEP(19,0,0,0); } while (0)
#define WIN5 do { JSTEP(20,2,2,1); JSTEP(21,0,0,1); JSTEP(22,2,2,1); JSTEP(23,0,0,1); } while (0)

  // 7 phases, Y lags X by one window. Barriers are block-uniform (outside the
  // side branch). Inside each phase the side==0/1 test folds the dead half of
  // JSTEP away (side is wave-uniform).
  if (side == 0) { WIN0; }
  __syncthreads();
  if (side == 0) { WIN1; } else { WIN0; }
  __syncthreads();
  if (side == 0) { WIN2; } else { WIN1; }
  __syncthreads();
  if (side == 0) { WIN3; } else { WIN2; }
  __syncthreads();
  if (side == 0) { WIN4; } else { WIN3; }
  __syncthreads();
  if (side == 0) { WIN5; } else { WIN4; }
  __syncthreads();
  if (side == 1) { WIN5; }
#undef WIN0
#undef WIN1
#undef WIN2
#undef WIN3
#undef WIN4
#undef WIN5
#undef JSTEP
#undef ROOTSTEP

  // Y-wave holds every squared-diff exactly once -> same constants as rounds 7-11
  const float c_rot = 1.0f / ((float)NROWS * NJ * 4);   // B1 * mean over (bs,T,24,4)
  const float c_gtr = 2.5f / ((float)NROWS * NJ * 3);   // B2 * 2.5 * mean over (bs,T,24,3)
  const float c_pos = 1.0f / ((float)NROWS * 3);        // B2 * mean over (bs,T,3)
  float contrib = c_rot * rot_acc + c_gtr * gtr_acc + c_pos * pos_acc;
#pragma unroll
  for (int o = 32; o > 0; o >>= 1) contrib += __shfl_down(contrib, o, 64);
  if (side == 1 && t == 0) atomicAdd(out, contrib);
}

extern "C" void kernel_launch(void* const* d_in, const int* in_sizes, int n_in,
                              void* d_out, int out_size, void* d_ws, size_t ws_size,
                              hipStream_t stream) {
  const float* Ym = (const float*)d_in[0];
  const float* Xm = (const float*)d_in[1];
  const float* Yt = (const float*)d_in[2];
  const float* Xt = (const float*)d_in[3];
  float* out = (float*)d_out;
  hipMemsetAsync(out, 0, sizeof(float), stream);  // graph-capturable
  motion_loss_kernel<<<NROWS / RPB, BLOCK, 0, stream>>>(Ym, Xm, Yt, Xt, out);
}